// Round 1
// 178.095 us; speedup vs baseline: 1.0293x; 1.0293x over previous
//
#include <hip/hip_runtime.h>

// GroupedConv2d via bf16 MFMA implicit GEMM — row-ring pipelined version.
// G=8 groups x 32 gathered channels -> J=64, 3x3 pad=1.
// x[16,256,56,56] fp32 -> out[16,512,56,56] fp32.
//
// Block = (g, b, chunk of 8 output rows = 4 two-row bands). 4 waves; wave jt
// owns 16 j's. LDS holds an 8-slot ring of input ROWS (slot = input_row & 7,
// 58 px x 40 shorts each); each band stages only the 2 NEW rows it needs
// (float4 loads, channel-pair packed) while computing the current band.
// Halo columns (input col -1 / 56) are always zero -> zeroed once at init.
// 37.1 KB LDS + VGPR<=128 -> 4 blocks/CU, 896 blocks all co-resident.

#define NG 8
#define CPER 32
#define CIN 256
#define NJ 64
#define NB 16
#define NH 56
#define NW 56
#define PXST 40                    // shorts per LDS pixel (32 ch + 8 pad) = 80 B
#define SLOT_SH (58 * PXST)        // 2320 shorts per row-slot
#define RING_SH (8 * SLOT_SH)      // 18560 shorts = 37120 B
#define WEI_SH (9 * 2048)          // 18432 shorts (fits inside the ring region)

typedef __attribute__((ext_vector_type(8))) short short8v;
typedef __attribute__((ext_vector_type(4))) float float4v;

__device__ __forceinline__ unsigned bf16rne(float f) {
    unsigned u = __float_as_uint(f);
    return (u + 0x7FFFu + ((u >> 16) & 1u)) >> 16;
}

__global__ __launch_bounds__(256, 4)
void gconv_mfma(const float* __restrict__ x,
                const float* __restrict__ w,
                const float* __restrict__ bias,
                const int* __restrict__ arr,
                float* __restrict__ out) {
    __shared__ __align__(16) unsigned short smem[RING_SH];

    const int tid   = threadIdx.x;
    const int chunk = blockIdx.x;      // 0..6 -> output rows [chunk*8, chunk*8+8)
    const int b     = blockIdx.y;
    const int g     = blockIdx.z;
    const int lane  = tid & 63;
    const int jt    = tid >> 6;        // wave id = j-tile
    const int n     = lane & 15;       // pixel-in-tile / j-in-tile
    const int kq    = lane >> 4;       // k-quarter (channels kq*8..kq*8+7)
    const int rbase = chunk * 8;

    // ---- stage weights: coalesced global read -> LDS [tap][j*32+c] bf16 ----
    {
        const float* wg = w + (size_t)g * (NJ * CPER * 9);
        for (int e = tid; e < WEI_SH; e += 256) {
            int jc = e / 9, tap = e - jc * 9;
            smem[tap * 2048 + jc] = (unsigned short)bf16rne(wg[e]);
        }
    }
    __syncthreads();
    short8v A[9];
    {
        const unsigned short* wl = smem + (jt * 16 + n) * CPER + kq * 8;
        #pragma unroll
        for (int t = 0; t < 9; ++t) A[t] = *(const short8v*)(wl + t * 2048);
    }
    float4v binit;
    #pragma unroll
    for (int i = 0; i < 4; ++i) binit[i] = bias[g * NJ + jt * 16 + kq * 4 + i];
    __syncthreads();   // weight region now reusable as the row ring

    const float* xb = x + (size_t)b * (CIN * NH * NW);

    // ---- zero halo columns (LDS cols 0 and 57 of all 8 slots): 256 dwords ----
    {
        int s = tid >> 5, rm = tid & 31;
        int colsel = (rm >> 4) ? 57 : 0;
        int c = rm & 15;
        *(unsigned*)(&smem[s * SLOT_SH + colsel * PXST + c * 2]) = 0u;
    }

    // ---- init stage: input rows rbase-1 .. rbase+2 into their ring slots ----
    #pragma unroll
    for (int k = 0; k < 4; ++k) {
        int t = tid + 256 * k;
        if (t < 896) {                       // 16 pairs x 4 rows x 14 col-groups
            int c2 = t / 56, rem = t - c2 * 56;
            int r4 = rem / 14, gc = rem - r4 * 14;
            int ch0 = arr[g * CPER + 2 * c2], ch1 = arr[g * CPER + 2 * c2 + 1];
            int row = rbase - 1 + r4;
            float4v v0 = 0.f, v1 = 0.f;
            if ((unsigned)row < NH) {
                v0 = *(const float4v*)(xb + ch0 * (NH * NW) + row * NW + 4 * gc);
                v1 = *(const float4v*)(xb + ch1 * (NH * NW) + row * NW + 4 * gc);
            }
            unsigned short* d = smem + (row & 7) * SLOT_SH + (1 + 4 * gc) * PXST + 2 * c2;
            #pragma unroll
            for (int i = 0; i < 4; ++i)
                *(unsigned*)(d + i * PXST) = bf16rne(v0[i]) | (bf16rne(v1[i]) << 16);
        }
    }

    // ---- per-thread band-prefetch descriptors (2 tasks: t=tid, t=tid+256) ----
    int gof0[2], gof1[2], ldc[2], rho[2];
    #pragma unroll
    for (int k = 0; k < 2; ++k) {
        int t  = tid + 256 * k;
        int tt = (t < 448) ? t : 0;          // clamped; inactive guarded at use
        int c2 = tt / 28, rem = tt - c2 * 28;
        int rh = rem / 14, gc = rem - rh * 14;
        gof0[k] = arr[g * CPER + 2 * c2] * (NH * NW) + 4 * gc;
        gof1[k] = arr[g * CPER + 2 * c2 + 1] * (NH * NW) + 4 * gc;
        ldc[k]  = (1 + 4 * gc) * PXST + 2 * c2;
        rho[k]  = rh;
    }
    const bool act1 = (tid < 192);
    __syncthreads();

    // ---- band loop: 4 bands of 2 output rows ----
    for (int bd = 0; bd < 4; ++bd) {
        const int r0 = rbase + 2 * bd;
        const bool dopf = (bd < 3);

        // phase A: issue next band's loads (rows r0+3, r0+4) — no wait here
        float4v pfa0 = 0.f, pfa1 = 0.f, pfb0 = 0.f, pfb1 = 0.f;
        if (dopf) {
            int rowA = r0 + 3 + rho[0];
            if (rowA < NH) {
                pfa0 = *(const float4v*)(xb + gof0[0] + rowA * NW);
                pfa1 = *(const float4v*)(xb + gof1[0] + rowA * NW);
            }
            if (act1) {
                int rowB = r0 + 3 + rho[1];
                if (rowB < NH) {
                    pfb0 = *(const float4v*)(xb + gof0[1] + rowB * NW);
                    pfb1 = *(const float4v*)(xb + gof1[1] + rowB * NW);
                }
            }
        }
        __builtin_amdgcn_sched_barrier(0);

        // phase B: compute current band from ring slots (r0-1 .. r0+2)
        {
            const int obase = ((b * (NG * NJ) + g * NJ + jt * 16 + kq * 4) * NH + r0) * NW;
            const int sb0 = ((r0 - 1) & 7) * SLOT_SH;
            const int sb1 = ((r0    ) & 7) * SLOT_SH;
            const int sb2 = ((r0 + 1) & 7) * SLOT_SH;
            const int sb3 = ((r0 + 2) & 7) * SLOT_SH;
            int rl = 0, col = n, coff = n * PXST + kq * 8;
            #pragma unroll
            for (int tp = 0; tp < 3; ++tp) {
                const int rlA = rl, colA = col, cfA = coff;
                col += 16; coff += 16 * PXST; if (col >= NW) { col -= NW; coff -= NW * PXST; ++rl; }
                const int rlB = rl, colB = col, cfB = coff;
                col += 16; coff += 16 * PXST; if (col >= NW) { col -= NW; coff -= NW * PXST; ++rl; }
                const unsigned short* a0p = smem + ((rlA ? sb1 : sb0) + cfA);
                const unsigned short* a1p = smem + ((rlA ? sb2 : sb1) + cfA);
                const unsigned short* a2p = smem + ((rlA ? sb3 : sb2) + cfA);
                const unsigned short* b0p = smem + ((rlB ? sb1 : sb0) + cfB);
                const unsigned short* b1p = smem + ((rlB ? sb2 : sb1) + cfB);
                const unsigned short* b2p = smem + ((rlB ? sb3 : sb2) + cfB);
                float4v a0 = binit, a1 = binit;
                #pragma unroll
                for (int kw = 0; kw < 3; ++kw) {
                    short8v x0 = *(const short8v*)(a0p + kw * PXST);
                    short8v y0 = *(const short8v*)(b0p + kw * PXST);
                    a0 = __builtin_amdgcn_mfma_f32_16x16x32_bf16(A[kw],     x0, a0, 0, 0, 0);
                    a1 = __builtin_amdgcn_mfma_f32_16x16x32_bf16(A[kw],     y0, a1, 0, 0, 0);
                    short8v x1 = *(const short8v*)(a1p + kw * PXST);
                    short8v y1 = *(const short8v*)(b1p + kw * PXST);
                    a0 = __builtin_amdgcn_mfma_f32_16x16x32_bf16(A[3 + kw], x1, a0, 0, 0, 0);
                    a1 = __builtin_amdgcn_mfma_f32_16x16x32_bf16(A[3 + kw], y1, a1, 0, 0, 0);
                    short8v x2 = *(const short8v*)(a2p + kw * PXST);
                    short8v y2 = *(const short8v*)(b2p + kw * PXST);
                    a0 = __builtin_amdgcn_mfma_f32_16x16x32_bf16(A[6 + kw], x2, a0, 0, 0, 0);
                    a1 = __builtin_amdgcn_mfma_f32_16x16x32_bf16(A[6 + kw], y2, a1, 0, 0, 0);
                }
                const int obA = obase + rlA * NW + colA;
                const int obB = obase + rlB * NW + colB;
                #pragma unroll
                for (int i = 0; i < 4; ++i) {
                    __builtin_nontemporal_store(a0[i], &out[obA + i * (NH * NW)]);
                    __builtin_nontemporal_store(a1[i], &out[obB + i * (NH * NW)]);
                }
            }
            // tile 6 (single)
            const unsigned short* a0p = smem + ((rl ? sb1 : sb0) + coff);
            const unsigned short* a1p = smem + ((rl ? sb2 : sb1) + coff);
            const unsigned short* a2p = smem + ((rl ? sb3 : sb2) + coff);
            float4v a0 = binit;
            #pragma unroll
            for (int kw = 0; kw < 3; ++kw) {
                short8v x0 = *(const short8v*)(a0p + kw * PXST);
                a0 = __builtin_amdgcn_mfma_f32_16x16x32_bf16(A[kw],     x0, a0, 0, 0, 0);
                short8v x1 = *(const short8v*)(a1p + kw * PXST);
                a0 = __builtin_amdgcn_mfma_f32_16x16x32_bf16(A[3 + kw], x1, a0, 0, 0, 0);
                short8v x2 = *(const short8v*)(a2p + kw * PXST);
                a0 = __builtin_amdgcn_mfma_f32_16x16x32_bf16(A[6 + kw], x2, a0, 0, 0, 0);
            }
            const int obA = obase + rl * NW + col;
            #pragma unroll
            for (int i = 0; i < 4; ++i)
                __builtin_nontemporal_store(a0[i], &out[obA + i * (NH * NW)]);
        }

        // phase C: convert + write the prefetched rows into their ring slots
        if (dopf) {
            {
                int rowA = r0 + 3 + rho[0];
                unsigned short* d = smem + (rowA & 7) * SLOT_SH + ldc[0];
                #pragma unroll
                for (int i = 0; i < 4; ++i)
                    *(unsigned*)(d + i * PXST) = bf16rne(pfa0[i]) | (bf16rne(pfa1[i]) << 16);
            }
            if (act1) {
                int rowB = r0 + 3 + rho[1];
                unsigned short* d = smem + (rowB & 7) * SLOT_SH + ldc[1];
                #pragma unroll
                for (int i = 0; i < 4; ++i)
                    *(unsigned*)(d + i * PXST) = bf16rne(pfb0[i]) | (bf16rne(pfb1[i]) << 16);
            }
            __syncthreads();
        }
    }
}

extern "C" void kernel_launch(void* const* d_in, const int* in_sizes, int n_in,
                              void* d_out, int out_size, void* d_ws, size_t ws_size,
                              hipStream_t stream) {
    const float* x    = (const float*)d_in[0];
    const float* wght = (const float*)d_in[1];
    const float* bias = (const float*)d_in[2];
    const int*   arr  = (const int*)d_in[3];
    float* out = (float*)d_out;

    dim3 grid(7, NB, NG);   // 7 row-chunks x batch x group = 896 blocks (~4/CU)
    gconv_mfma<<<grid, 256, 0, stream>>>(x, wght, bias, arr, out);
}

// Round 2
// 172.849 us; speedup vs baseline: 1.0605x; 1.0304x over previous
//
#include <hip/hip_runtime.h>

// GroupedConv2d via bf16 MFMA implicit GEMM — j-reuse-2, flat 10-row stage.
// G=8 groups x 32 gathered channels -> J=64, 3x3 pad=1.
// x[16,256,56,56] fp32 -> out[16,512,56,56] fp32.
//
// Block = (g, b, chunk of 8 output rows). 4 waves = (j-half) x (row-half).
// Each wave holds TWO j-tiles' weights in registers (A[2][9], 72 VGPR) and
// applies every LDS pixel fragment to both -> LDS read traffic halved vs
// one-jt-per-wave (the round-1 bottleneck: ~70% of runtime was LDS pipe).
// All 10 input rows (rbase-1..rbase+8) staged once into a flat slot array
// (46.4 KB), single barrier, then barrier-free compute: per 16-px tile one
// per-lane base pointer + 9 compile-time ds_read offsets (kh*4640+kw*80 B).
// Plain stores (NT caused 14% write amplification). 3 blocks/CU.

#define NG 8
#define CPER 32
#define CIN 256
#define NJ 64
#define NB 16
#define NH 56
#define NW 56
#define PXSH 40                    // shorts per LDS pixel (32 ch + 8 pad) = 80 B
#define SLOT_SH (58 * PXSH)        // 2320 shorts per row-slot
#define NSLOT 10
#define BUF_SH (NSLOT * SLOT_SH)   // 23200 shorts = 46400 B
#define WEI_SH (9 * 2048)          // 18432 shorts (reuses slot region)
#define NTASK 2240                 // 16 chpairs x 10 rows x 14 col-groups
#define KMAX 9                     // ceil(2240/256)

typedef __attribute__((ext_vector_type(8))) short short8v;
typedef __attribute__((ext_vector_type(4))) float float4v;

__device__ __forceinline__ unsigned bf16rne(float f) {
    unsigned u = __float_as_uint(f);
    return (u + 0x7FFFu + ((u >> 16) & 1u)) >> 16;
}

#define MFMA __builtin_amdgcn_mfma_f32_16x16x32_bf16

__global__ __launch_bounds__(256, 3)
void gconv_mfma(const float* __restrict__ x,
                const float* __restrict__ w,
                const float* __restrict__ bias,
                const int* __restrict__ arr,
                float* __restrict__ out) {
    __shared__ __align__(16) unsigned short smem[BUF_SH];

    const int tid   = threadIdx.x;
    const int chunk = blockIdx.x;      // 0..6 -> output rows [chunk*8, chunk*8+8)
    const int b     = blockIdx.y;
    const int g     = blockIdx.z;
    const int lane  = tid & 63;
    const int wid   = tid >> 6;
    const int n     = lane & 15;       // pixel-in-tile / j-in-tile
    const int kq    = lane >> 4;       // k-quarter (channels kq*8..kq*8+7)
    const int jh    = wid & 1;         // j-half: j in [32*jh, 32*jh+32)
    const int ph    = wid >> 1;        // row-half: bands {2*ph, 2*ph+1}
    const int rbase = chunk * 8;

    // ---- stage weights: coalesced global read -> LDS [tap][j*32+c] bf16 ----
    {
        const float* wg = w + (size_t)g * (NJ * CPER * 9);
        for (int e = tid; e < WEI_SH; e += 256) {
            int jc = e / 9, tap = e - jc * 9;
            smem[tap * 2048 + jc] = (unsigned short)bf16rne(wg[e]);
        }
    }
    __syncthreads();
    short8v A[2][9];                   // two j-tiles per wave
    #pragma unroll
    for (int jt2 = 0; jt2 < 2; ++jt2) {
        const unsigned short* wl = smem + ((2 * jh + jt2) * 16 + n) * CPER + kq * 8;
        #pragma unroll
        for (int t = 0; t < 9; ++t) A[jt2][t] = *(const short8v*)(wl + t * 2048);
    }
    float4v binit[2];
    #pragma unroll
    for (int jt2 = 0; jt2 < 2; ++jt2)
        #pragma unroll
        for (int i = 0; i < 4; ++i)
            binit[jt2][i] = bias[g * NJ + (2 * jh + jt2) * 16 + kq * 4 + i];
    __syncthreads();   // weight region now reusable as pixel slots

    // ---- zero halo columns (LDS px 0 and 57 of all 10 slots) ----
    for (int z = tid; z < 320; z += 256) {
        int s = z >> 5, rm = z & 31;
        int col = (rm >> 4) ? 57 : 0, cd = rm & 15;
        *(unsigned*)(&smem[s * SLOT_SH + col * PXSH + cd * 2]) = 0u;
    }

    // ---- staging descriptors: task = (chpair c2, local row lr, col-group gc) ----
    const float* xb = x + (size_t)b * (CIN * NH * NW);
    int xo0[KMAX], xo1[KMAX], wof[KMAX];
    bool vr[KMAX], act[KMAX];
    #pragma unroll
    for (int k = 0; k < KMAX; ++k) {
        int tk = tid + 256 * k;
        act[k] = tk < NTASK;
        int tt = act[k] ? tk : 0;
        int c2 = tt / 140, rem = tt - c2 * 140;
        int lr = rem / 14, gc = rem - lr * 14;
        int irow = rbase - 1 + lr;
        vr[k] = (unsigned)irow < NH;
        int ro = irow * NW + 4 * gc;
        xo0[k] = arr[g * CPER + 2 * c2] * (NH * NW) + ro;
        xo1[k] = arr[g * CPER + 2 * c2 + 1] * (NH * NW) + ro;
        wof[k] = lr * SLOT_SH + (1 + 4 * gc) * PXSH + 2 * c2;
    }

    // ---- staged load (2-deep rotation; compiler inserts counted vmcnt) ----
    float4v va[2], vb[2];
    #pragma unroll
    for (int k = 0; k < 2; ++k) {
        float4v t0 = 0.f, t1 = 0.f;
        if (vr[k]) {
            t0 = *(const float4v*)(xb + xo0[k]);
            t1 = *(const float4v*)(xb + xo1[k]);
        }
        va[k] = t0; vb[k] = t1;
    }
    #pragma unroll
    for (int k = 0; k < KMAX; ++k) {
        if (act[k]) {
            unsigned short* d = smem + wof[k];
            #pragma unroll
            for (int i = 0; i < 4; ++i)
                *(unsigned*)(d + i * PXSH) =
                    bf16rne(va[k & 1][i]) | (bf16rne(vb[k & 1][i]) << 16);
        }
        if (k + 2 < KMAX) {
            int kk = k + 2;                // kk & 1 == k & 1
            float4v t0 = 0.f, t1 = 0.f;
            if (vr[kk]) {
                t0 = *(const float4v*)(xb + xo0[kk]);
                t1 = *(const float4v*)(xb + xo1[kk]);
            }
            va[k & 1] = t0; vb[k & 1] = t1;
        }
    }
    __syncthreads();

    // ---- compute: 2 bands per wave, barrier-free ----
    #pragma unroll
    for (int band2 = 0; band2 < 2; ++band2) {
        const int band = ph * 2 + band2;
        const int r0 = rbase + 2 * band;
        // pixel (out-row r0+rl, col c), tap (kh,kw) lives at
        // slot (2*band + rl + kh), px (c + kw)  -> base + kh*SLOT_SH + kw*PXSH
        const unsigned short* base = smem + (2 * band) * SLOT_SH + kq * 8;
        const int ob0 = ((b * (NG * NJ) + g * NJ + jh * 32 + kq * 4) * NH + r0) * NW;
        const int ob1 = ob0 + 16 * NH * NW;     // second j-tile (+16 channels)
        int rl = 0, col = n;
        #pragma unroll
        for (int tp = 0; tp < 3; ++tp) {
            const int rlA = rl, colA = col;
            col += 16; if (col >= NW) { col -= NW; ++rl; }
            const int rlB = rl, colB = col;
            col += 16; if (col >= NW) { col -= NW; ++rl; }
            const unsigned short* pA = base + rlA * SLOT_SH + colA * PXSH;
            const unsigned short* pB = base + rlB * SLOT_SH + colB * PXSH;
            float4v a00 = binit[0], a01 = binit[1];
            float4v a10 = binit[0], a11 = binit[1];
            #pragma unroll
            for (int kh = 0; kh < 3; ++kh)
                #pragma unroll
                for (int kw = 0; kw < 3; ++kw) {
                    short8v x0 = *(const short8v*)(pA + kh * SLOT_SH + kw * PXSH);
                    short8v y0 = *(const short8v*)(pB + kh * SLOT_SH + kw * PXSH);
                    a00 = MFMA(A[0][kh * 3 + kw], x0, a00, 0, 0, 0);
                    a01 = MFMA(A[1][kh * 3 + kw], x0, a01, 0, 0, 0);
                    a10 = MFMA(A[0][kh * 3 + kw], y0, a10, 0, 0, 0);
                    a11 = MFMA(A[1][kh * 3 + kw], y0, a11, 0, 0, 0);
                }
            const int oA = rlA * NW + colA, oB = rlB * NW + colB;
            #pragma unroll
            for (int i = 0; i < 4; ++i) {
                out[ob0 + oA + i * (NH * NW)] = a00[i];
                out[ob1 + oA + i * (NH * NW)] = a01[i];
                out[ob0 + oB + i * (NH * NW)] = a10[i];
                out[ob1 + oB + i * (NH * NW)] = a11[i];
            }
        }
        // tile 6 (single)
        const unsigned short* pA = base + rl * SLOT_SH + col * PXSH;
        float4v a00 = binit[0], a01 = binit[1];
        #pragma unroll
        for (int kh = 0; kh < 3; ++kh)
            #pragma unroll
            for (int kw = 0; kw < 3; ++kw) {
                short8v x0 = *(const short8v*)(pA + kh * SLOT_SH + kw * PXSH);
                a00 = MFMA(A[0][kh * 3 + kw], x0, a00, 0, 0, 0);
                a01 = MFMA(A[1][kh * 3 + kw], x0, a01, 0, 0, 0);
            }
        const int oA = rl * NW + col;
        #pragma unroll
        for (int i = 0; i < 4; ++i) {
            out[ob0 + oA + i * (NH * NW)] = a00[i];
            out[ob1 + oA + i * (NH * NW)] = a01[i];
        }
    }
}

extern "C" void kernel_launch(void* const* d_in, const int* in_sizes, int n_in,
                              void* d_out, int out_size, void* d_ws, size_t ws_size,
                              hipStream_t stream) {
    const float* x    = (const float*)d_in[0];
    const float* wght = (const float*)d_in[1];
    const float* bias = (const float*)d_in[2];
    const int*   arr  = (const int*)d_in[3];
    float* out = (float*)d_out;

    dim3 grid(7, NB, NG);   // 7 row-chunks x batch x group = 896 blocks (~3/CU)
    gconv_mfma<<<grid, 256, 0, stream>>>(x, wght, bias, arr, out);
}